// Round 8
// baseline (294.162 us; speedup 1.0000x reference)
//
#include <hip/hip_runtime.h>

// ---------------------------------------------------------------------------
// MAB block: Qp=Q@Wq^T+bq; Kp/Vp from K; O=softmax(QhKh^T/8)Vh; X=LN(O+Qp);
// h1=relu(X@W1^T+b1); h2=relu(h1@W2^T+b2); Off=h2@W3^T+b3; out=LN(X+Off).
// GEMMs bf16 MFMA 16x16x32 (BK=64, XOR-swizzled LDS); FFN2 in fp8 e4m3 via
// mfma_scale_f32_32x32x64_f8f6f4 with identity scales.
// R7: attn rework -- XCD-locality block swizzle (idx%8==h keeps each (b,h)'s
//     K/VT slice on one XCD's L2; 2 MB working set), register-staged double
//     buffer (global_load_dwordx4 -> VGPR -> ds_write_b128: barrier needs only
//     lgkmcnt, prefetch loads stay in flight across compute), 64-m tiles
//     (LDS 25.6 KB -> 4 blocks/CU).
// ---------------------------------------------------------------------------

typedef __bf16 bf16_t;
typedef __bf16 bf16x8 __attribute__((ext_vector_type(8)));
typedef __bf16 bf16x4 __attribute__((ext_vector_type(4)));
typedef __bf16 bf16x2 __attribute__((ext_vector_type(2)));
typedef float  f32x4  __attribute__((ext_vector_type(4)));
typedef float  f32x16 __attribute__((ext_vector_type(16)));
typedef int    i32x4_t __attribute__((ext_vector_type(4)));
typedef int    i32x8_t __attribute__((ext_vector_type(8)));

__device__ __forceinline__ f32x4 mfma16(bf16x8 a, bf16x8 b, f32x4 c) {
  return __builtin_amdgcn_mfma_f32_16x16x32_bf16(a, b, c, 0, 0, 0);
}

// async global->LDS, 16B per lane. LDS dst is wave-uniform base + lane*16.
__device__ __forceinline__ void gload_lds16(const void* g, void* l) {
  __builtin_amdgcn_global_load_lds((const __attribute__((address_space(1))) void*)g,
                                   (__attribute__((address_space(3))) void*)l,
                                   16, 0, 0);
}

__device__ __forceinline__ unsigned char to_fp8(float v) {
  return (unsigned char)(__builtin_amdgcn_cvt_pk_fp8_f32(v, v, 0, false) & 0xff);
}

// ---------------------------------------------------------------------------
// Fused f32 -> bf16 cast of Q, K and weights; W2 -> fp8 e4m3.
// ---------------------------------------------------------------------------
__global__ __launch_bounds__(256) void cast_all(
    const float* __restrict__ Q, const float* __restrict__ K,
    const float* __restrict__ Wq, const float* __restrict__ Wk,
    const float* __restrict__ Wv, const float* __restrict__ W1,
    const float* __restrict__ W2, const float* __restrict__ W3,
    bf16_t* Qb, bf16_t* Kb, bf16_t* Wqb, bf16_t* Wkb, bf16_t* Wvb,
    bf16_t* W1b, unsigned char* W2q, bf16_t* W3b)
{
  long i = ((long)blockIdx.x * 256 + threadIdx.x) * 4;
  if (i >= 10223616L && i < 14417920L) {          // W2 -> fp8
    long o = i - 10223616L;
    float4 v = *(const float4*)(W2 + o);
    unsigned int lo = __builtin_amdgcn_cvt_pk_fp8_f32(v.x, v.y, 0, false);
    unsigned int hi = __builtin_amdgcn_cvt_pk_fp8_f32(v.z, v.w, 0, false);
    *(unsigned int*)(W2q + o) = (lo & 0xffffu) | (hi << 16);
    return;
  }
  const float* s; bf16_t* d; long o;
  if      (i <  4194304L) { s = Q;  d = Qb;  o = i;             }
  else if (i <  8388608L) { s = K;  d = Kb;  o = i - 4194304L;  }
  else if (i <  8650752L) { s = Wq; d = Wqb; o = i - 8388608L;  }
  else if (i <  8912896L) { s = Wk; d = Wkb; o = i - 8650752L;  }
  else if (i <  9175040L) { s = Wv; d = Wvb; o = i - 8912896L;  }
  else if (i < 10223616L) { s = W1; d = W1b; o = i - 9175040L;  }
  else                    { s = W3; d = W3b; o = i - 14417920L; }
  float4 v = *(const float4*)(s + o);
  bf16x4 w;
  w[0] = (bf16_t)v.x; w[1] = (bf16_t)v.y; w[2] = (bf16_t)v.z; w[3] = (bf16_t)v.w;
  *(bf16x4*)(d + o) = w;
}

// ---------------------------------------------------------------------------
// bf16 GEMM core: C[M,N] = A[M,Ktile] @ W[N,Ktile]^T (+bias, opt relu).
// BN=128, BK=64. LDS rows 128B, chunk c of row r at slot c^(r&7).
// Outputs: f32 (Cf), bf16*bscale (Cb), fp8 (C8), or transposed-VT (VTout).
// ---------------------------------------------------------------------------
template <int BM, bool RELU, bool VTEPI>
__device__ __forceinline__ void gemm_core(
    const bf16_t* __restrict__ A, const bf16_t* __restrict__ W,
    const float* __restrict__ bias, float* __restrict__ Cf,
    bf16_t* __restrict__ Cb, unsigned char* __restrict__ C8,
    bf16_t* __restrict__ VTout,
    float bscale, int N, int K, int lda, int ldb, int bx, int by)
{
  constexpr int WM = (BM == 128) ? 2 : 1;
  constexpr int WN = 4 / WM;
  constexpr int FI = 4;
  constexpr int FJ = 128 / (WN * 16);
  constexpr int CN = 128 / WN;
  constexpr int AISS = BM / 32;
  constexpr int SM_AB = (BM + 128) * 64 * 2;
  constexpr int SM_TS = 128 * 132 * 2;
  constexpr int SMEM = (VTEPI && SM_TS > SM_AB) ? SM_TS : SM_AB;

  __shared__ __align__(16) char smem[SMEM];
  bf16_t* As = (bf16_t*)smem;
  bf16_t* Bs = (bf16_t*)(smem + BM * 64 * 2);

  const int tid  = threadIdx.x;
  const int wave = tid >> 6, lane = tid & 63;
  const int lq   = lane & 15, quad = lane >> 4;
  const int wm   = (WM == 2) ? (wave & 1) : 0;
  const int wn   = (WM == 2) ? (wave >> 1) : wave;
  const long row0 = (long)bx * BM;
  const long col0 = (long)by * 128;

  const int sr = tid >> 3;
  const int cg = (tid & 7) ^ (sr & 7);
  const bf16_t* ag = A + (row0 + sr) * (long)lda + cg * 8;
  const bf16_t* bg = W + (col0 + sr) * (long)ldb + cg * 8;
  char* asD = (char*)As + wave * 1024;
  char* bsD = (char*)Bs + wave * 1024;

  const int off0 = (quad ^ (lq & 7)) * 8;
  const bf16_t* aR0 = As + (wm * 64 + lq) * 64 + off0;
  const bf16_t* aR1 = As + (wm * 64 + lq) * 64 + (off0 ^ 32);
  const bf16_t* bR0 = Bs + (wn * CN + lq) * 64 + off0;
  const bf16_t* bR1 = Bs + (wn * CN + lq) * 64 + (off0 ^ 32);

  f32x4 acc[FI][FJ];
#pragma unroll
  for (int i = 0; i < FI; i++)
#pragma unroll
    for (int j = 0; j < FJ; j++) acc[i][j] = (f32x4){0.f, 0.f, 0.f, 0.f};

  const long arows32 = 32L * lda;
  const long brows32 = 32L * ldb;
  for (int k0 = 0; k0 < K; k0 += 64) {
    __syncthreads();
#pragma unroll
    for (int is = 0; is < AISS; is++)
      gload_lds16(ag + is * arows32 + k0, asD + is * 4096);
#pragma unroll
    for (int is = 0; is < 4; is++)
      gload_lds16(bg + is * brows32 + k0, bsD + is * 4096);
    __syncthreads();
    bf16x8 af[FI], bw[FJ];
#pragma unroll
    for (int i = 0; i < FI; i++) af[i] = *(const bf16x8*)(aR0 + i * 1024);
#pragma unroll
    for (int j = 0; j < FJ; j++) bw[j] = *(const bf16x8*)(bR0 + j * 1024);
#pragma unroll
    for (int i = 0; i < FI; i++)
#pragma unroll
      for (int j = 0; j < FJ; j++)
        acc[i][j] = mfma16(af[i], bw[j], acc[i][j]);
#pragma unroll
    for (int i = 0; i < FI; i++) af[i] = *(const bf16x8*)(aR1 + i * 1024);
#pragma unroll
    for (int j = 0; j < FJ; j++) bw[j] = *(const bf16x8*)(bR1 + j * 1024);
#pragma unroll
    for (int i = 0; i < FI; i++)
#pragma unroll
      for (int j = 0; j < FJ; j++)
        acc[i][j] = mfma16(af[i], bw[j], acc[i][j]);
  }

  float bc[FJ];
#pragma unroll
  for (int j = 0; j < FJ; j++)
    bc[j] = bias ? bias[col0 + wn * CN + j * 16 + lq] : 0.f;

  if (VTEPI && VTout) {
    bf16_t* Ts = (bf16_t*)smem;
    __syncthreads();
#pragma unroll
    for (int i = 0; i < FI; i++)
#pragma unroll
      for (int j = 0; j < FJ; j++) {
        bf16x4 pv;
#pragma unroll
        for (int r = 0; r < 4; r++) pv[r] = (bf16_t)(acc[i][j][r] + bc[j]);
        *(bf16x4*)(Ts + (wn * CN + j * 16 + lq) * 132 + wm * 64 + i * 16 + quad * 4) = pv;
      }
    __syncthreads();
    const int b  = bx >> 3;
    const int mb = (bx & 7) * 128;
    const int h0 = by * 2;
    const int dd = tid >> 4;
    const int mc = (tid & 15) * 8;
#pragma unroll
    for (int p = 0; p < 8; p++) {
      const int d = dd + p * 16;
      bf16x8 v = *(const bf16x8*)(Ts + d * 132 + mc);
      *(bf16x8*)(VTout + ((long)(b * 8 + h0 + (d >> 6))) * 65536
                 + (d & 63) * 1024 + mb + mc) = v;
    }
    return;
  }

  const long rb = row0 + wm * 64 + quad * 4;
  const long cb = col0 + wn * CN + lq;
#pragma unroll
  for (int i = 0; i < FI; i++)
#pragma unroll
    for (int j = 0; j < FJ; j++)
#pragma unroll
      for (int r = 0; r < 4; r++) {
        float v = acc[i][j][r] + bc[j];
        if (RELU) v = fmaxf(v, 0.f);
        long idx = (rb + i * 16 + r) * (long)N + cb + j * 16;
        if (Cf) Cf[idx] = v;
        if (Cb) Cb[idx] = (bf16_t)(v * bscale);
        if (C8) C8[idx] = to_fp8(v);
      }
}

template <int BM, bool RELU>
__global__ __launch_bounds__(256) void gemm_bt(
    const bf16_t* __restrict__ A, const bf16_t* __restrict__ W,
    const float* __restrict__ bias, float* __restrict__ Cf,
    bf16_t* __restrict__ Cb, unsigned char* __restrict__ C8,
    float bscale, int N, int K)
{
  gemm_core<BM, RELU, false>(A, W, bias, Cf, Cb, C8, nullptr, bscale,
                             N, K, K, K, blockIdx.x, blockIdx.y);
}

// FFN3 split-K: z = K-half. Each block 128x128x1024; bf16 partial, no bias.
__global__ __launch_bounds__(256) void ffn3_splitk(
    const bf16_t* __restrict__ H2, const bf16_t* __restrict__ W3b,
    bf16_t* __restrict__ Off01)
{
  const int z = blockIdx.z;
  gemm_core<128, false, false>(H2 + z * 1024, W3b + z * 1024, nullptr,
                               nullptr, Off01 + (long)z * 4194304, nullptr,
                               nullptr, 1.0f, 512, 1024, 2048, 2048,
                               blockIdx.x, blockIdx.y);
}

// Fused Q/K/V projection; z==2 (V) writes transposed VT via VTEPI epilogue.
__global__ __launch_bounds__(256) void proj3(
    const bf16_t* __restrict__ Qb, const bf16_t* __restrict__ Kb,
    const bf16_t* __restrict__ Wqb, const bf16_t* __restrict__ Wkb,
    const bf16_t* __restrict__ Wvb,
    const float* __restrict__ bq, const float* __restrict__ bk,
    const float* __restrict__ bv,
    bf16_t* Qpb, bf16_t* Kpb, bf16_t* VT)
{
  const int z = blockIdx.z;
  const bf16_t* A  = (z == 0) ? Qb : Kb;
  const bf16_t* Wt = (z == 0) ? Wqb : ((z == 1) ? Wkb : Wvb);
  const float* bias = (z == 0) ? bq : ((z == 1) ? bk : bv);
  bf16_t* Cb = (z == 0) ? Qpb : ((z == 1) ? Kpb : nullptr);
  bf16_t* VTout = (z == 2) ? VT : nullptr;
  const float sc = (z == 1) ? 0.125f : 1.0f;
  gemm_core<128, false, true>(A, Wt, bias, nullptr, Cb, nullptr, VTout, sc,
                              512, 512, 512, 512, blockIdx.x, blockIdx.y);
}

// ---------------------------------------------------------------------------
// FFN2 in fp8: C[8192,2048] = relu(H1_fp8 @ W2_fp8^T + b2), bf16 out.
// mfma_scale_f32_32x32x64_f8f6f4, identity scales (0x7F = 2^0).
// ---------------------------------------------------------------------------
__global__ __launch_bounds__(256) void ffn2_fp8(
    const unsigned char* __restrict__ H1, const unsigned char* __restrict__ W2,
    const float* __restrict__ bias, bf16_t* __restrict__ C)
{
  __shared__ unsigned char As[16384];
  __shared__ unsigned char Bs[16384];
  const int tid = threadIdx.x;
  const int wave = tid >> 6, lane = tid & 63;
  const int wm = wave & 1, wn = wave >> 1;
  const int m = lane & 31, h = lane >> 5;
  const long row0 = (long)blockIdx.x * 128;
  const long col0 = (long)blockIdx.y * 128;

  const int sr = tid >> 3;
  const int cg = (tid & 7) ^ (sr & 7);
  const unsigned char* ag = H1 + (row0 + sr) * 2048 + cg * 16;
  const unsigned char* bg = W2 + (col0 + sr) * 2048 + cg * 16;
  char* asD = (char*)As + wave * 1024;
  char* bsD = (char*)Bs + wave * 1024;

  const int ar0 = wm * 64 + m, ar1 = ar0 + 32;
  const int br0 = wn * 64 + m, br1 = br0 + 32;

  f32x16 acc[2][2];
#pragma unroll
  for (int mi = 0; mi < 2; mi++)
#pragma unroll
    for (int nj = 0; nj < 2; nj++)
#pragma unroll
      for (int r = 0; r < 16; r++) acc[mi][nj][r] = 0.f;

  for (int k0 = 0; k0 < 2048; k0 += 128) {
    __syncthreads();
#pragma unroll
    for (int is = 0; is < 4; is++)
      gload_lds16(ag + is * 65536 + k0, asD + is * 4096);
#pragma unroll
    for (int is = 0; is < 4; is++)
      gload_lds16(bg + is * 65536 + k0, bsD + is * 4096);
    __syncthreads();
#pragma unroll
    for (int ks = 0; ks < 2; ks++) {
      const int c0 = ks * 4 + h * 2;
      i32x8_t a[2], b[2];
#pragma unroll
      for (int mi = 0; mi < 2; mi++) {
        const int r = mi ? ar1 : ar0;
        i32x4_t lo = *(const i32x4_t*)(As + r * 128 + ((c0    ) ^ (r & 7)) * 16);
        i32x4_t hi = *(const i32x4_t*)(As + r * 128 + ((c0 + 1) ^ (r & 7)) * 16);
        a[mi][0] = lo[0]; a[mi][1] = lo[1]; a[mi][2] = lo[2]; a[mi][3] = lo[3];
        a[mi][4] = hi[0]; a[mi][5] = hi[1]; a[mi][6] = hi[2]; a[mi][7] = hi[3];
      }
#pragma unroll
      for (int nj = 0; nj < 2; nj++) {
        const int r = nj ? br1 : br0;
        i32x4_t lo = *(const i32x4_t*)(Bs + r * 128 + ((c0    ) ^ (r & 7)) * 16);
        i32x4_t hi = *(const i32x4_t*)(Bs + r * 128 + ((c0 + 1) ^ (r & 7)) * 16);
        b[nj][0] = lo[0]; b[nj][1] = lo[1]; b[nj][2] = lo[2]; b[nj][3] = lo[3];
        b[nj][4] = hi[0]; b[nj][5] = hi[1]; b[nj][6] = hi[2]; b[nj][7] = hi[3];
      }
#pragma unroll
      for (int mi = 0; mi < 2; mi++)
#pragma unroll
        for (int nj = 0; nj < 2; nj++)
          acc[mi][nj] = __builtin_amdgcn_mfma_scale_f32_32x32x64_f8f6f4(
              a[mi], b[nj], acc[mi][nj], 0, 0,
              0, 0x7f7f7f7f, 0, 0x7f7f7f7f);
    }
  }

  float bc[2];
  bc[0] = bias[col0 + wn * 64 + m];
  bc[1] = bias[col0 + wn * 64 + 32 + m];
#pragma unroll
  for (int mi = 0; mi < 2; mi++)
#pragma unroll
    for (int nj = 0; nj < 2; nj++)
#pragma unroll
      for (int reg = 0; reg < 16; reg++) {
        const int rl = (reg & 3) + 8 * (reg >> 2) + 4 * h;
        float v = fmaxf(acc[mi][nj][reg] + bc[nj], 0.f);
        C[(row0 + wm * 64 + mi * 32 + rl) * 2048 + col0 + wn * 64 + nj * 32 + m]
            = (bf16_t)v;
      }
}

// ---------------------------------------------------------------------------
// Flash attention, fixed-max softmax. 1-D grid of 1024:
// idx = qb*64 + (b*8+h)  ->  idx%8 == h: all 16 q-blocks of a (b,h) share an
// XCD; K/VT slice (256 KB x 8 b = 2 MB) stays L2-resident.
// Register-staged double buffer: global_load_dwordx4 -> VGPR -> ds_write_b128.
// Barriers only need lgkmcnt (no LDS-dest vmem), so next-tile loads stay in
// flight across the whole compute phase. 64-m tiles, LDS 25.6 KB (4 blk/CU).
// ---------------------------------------------------------------------------
__global__ __launch_bounds__(256) void attn(
    const bf16_t* __restrict__ Qp, const bf16_t* __restrict__ Kp,
    const bf16_t* __restrict__ VT, bf16_t* __restrict__ O)
{
  const int idx = blockIdx.x;
  const int bh = idx & 63;          // b*8 + h
  const int qb = idx >> 6;
  const int b = bh >> 3, h = bh & 7;
  const int tid = threadIdx.x;
  const int wave = tid >> 6, lane = tid & 63;
  const int lq = lane & 15, quad = lane >> 4;

  __shared__ bf16_t Ks[4096];       // [64 m][64 d], 128B rows, slot c^(r&7)
  __shared__ bf16_t VTs[4096];      // [64 d][64 m]
  __shared__ bf16_t Ps[4][16 * 72]; // per-wave [16 q][64 m], stride 72

  const long bhl = (long)b * 1024;
  const int qrow = qb * 64 + wave * 16 + lq;
  const bf16_t* qptr = Qp + (bhl + qrow) * 512 + h * 64 + quad * 8;
  const bf16x8 qf0 = *(const bf16x8*)qptr;
  const bf16x8 qf1 = *(const bf16x8*)(qptr + 32);

  f32x4 oacc[4];
#pragma unroll
  for (int t = 0; t < 4; t++) oacc[t] = (f32x4){0.f, 0.f, 0.f, 0.f};
  float l_i = 0.f;

  // staging: thread t -> row sr=t>>3 (and sr+32), LDS slot t&7,
  // global chunk (t&7)^(sr&7). Consecutive-8 lanes: same row, 8 distinct
  // bank spans -> conflict-free b128 writes; 128B-coalesced global reads.
  const int sr = tid >> 3, slot = tid & 7;
  const int cg = slot ^ (sr & 7);
  const bf16_t* kg  = Kp + bhl * 512 + h * 64;
  const bf16_t* vtg = VT + (long)bh * 65536;
  const bf16_t* kp0 = kg + (long)sr * 512 + cg * 8;
  const bf16_t* kp1 = kg + (long)(sr + 32) * 512 + cg * 8;
  const bf16_t* vp0 = vtg + (long)sr * 1024 + cg * 8;
  const bf16_t* vp1 = vtg + (long)(sr + 32) * 1024 + cg * 8;

  bf16x8 rk0 = *(const bf16x8*)kp0;
  bf16x8 rk1 = *(const bf16x8*)kp1;
  bf16x8 rv0 = *(const bf16x8*)vp0;
  bf16x8 rv1 = *(const bf16x8*)vp1;

  bf16_t* ksW0 = Ks  + sr * 64 + slot * 8;
  bf16_t* ksW1 = Ks  + (sr + 32) * 64 + slot * 8;
  bf16_t* vtW0 = VTs + sr * 64 + slot * 8;
  bf16_t* vtW1 = VTs + (sr + 32) * 64 + slot * 8;

  for (int it = 0; it < 16; it++) {
    __syncthreads();                    // prev iter's LDS reads complete
    *(bf16x8*)ksW0 = rk0;
    *(bf16x8*)ksW1 = rk1;
    *(bf16x8*)vtW0 = rv0;
    *(bf16x8*)vtW1 = rv1;
    if (it < 15) {                      // prefetch next tile; stays in flight
      kp0 += 64 * 512; kp1 += 64 * 512; vp0 += 64; vp1 += 64;
      rk0 = *(const bf16x8*)kp0;
      rk1 = *(const bf16x8*)kp1;
      rv0 = *(const bf16x8*)vp0;
      rv1 = *(const bf16x8*)vp1;
    }
    __syncthreads();                    // LDS writes visible

    // S^T tiles: rows m (K tile = A-operand), cols q (Q regs = B-operand)
    f32x4 st[4];
#pragma unroll
    for (int t = 0; t < 4; t++) {
      const int mloc = t * 16 + lq;
      const int offK = (quad ^ (mloc & 7)) * 8;
      bf16x8 ka0 = *(const bf16x8*)(Ks + mloc * 64 + offK);
      bf16x8 ka1 = *(const bf16x8*)(Ks + mloc * 64 + (offK ^ 32));
      f32x4 s = (f32x4){0.f, 0.f, 0.f, 0.f};
      s = mfma16(ka0, qf0, s);
      s = mfma16(ka1, qf1, s);
      st[t] = s;
    }
    // fixed-max softmax: p = exp(s), accumulate l
    float lsum = 0.f;
#pragma unroll
    for (int t = 0; t < 4; t++)
#pragma unroll
      for (int r = 0; r < 4; r++) {
        float p = __expf(st[t][r]);
        st[t][r] = p;
        lsum += p;
      }
    lsum += __shfl_xor(lsum, 16, 64);
    lsum += __shfl_xor(lsum, 32, 64);
    l_i += lsum;

    // P -> per-wave LDS ([q][m], stride 72); same-wave lgkm ordering only
    bf16_t* pw = &Ps[wave][0];
#pragma unroll
    for (int t = 0; t < 4; t++) {
      bf16x4 pv;
#pragma unroll
      for (int r = 0; r < 4; r++) pv[r] = (bf16_t)st[t][r];
      *(bf16x4*)(pw + lq * 72 + t * 16 + quad * 4) = pv;
    }

    // O^T += V^T · P^T
#pragma unroll
    for (int ks = 0; ks < 2; ks++) {
      bf16x8 pb = *(const bf16x8*)(pw + lq * 72 + ks * 32 + quad * 8);
#pragma unroll
      for (int dt = 0; dt < 4; dt++) {
        const int row = dt * 16 + lq;
        const int offV = (quad ^ (row & 7)) * 8;
        bf16x8 va = *(const bf16x8*)(VTs + row * 64 + (ks ? (offV ^ 32) : offV));
        oacc[dt] = mfma16(va, pb, oacc[dt]);
      }
    }
  }

  const float inv = 1.f / l_i;
  bf16_t* op = O + (bhl + qrow) * 512 + h * 64 + quad * 4;
#pragma unroll
  for (int dt = 0; dt < 4; dt++) {
    bf16x4 v;
#pragma unroll
    for (int r = 0; r < 4; r++) v[r] = (bf16_t)(oacc[dt][r] * inv);
    *(bf16x4*)(op + dt * 16) = v;
  }
}

// ---------------------------------------------------------------------------
// LN kernels. ln_res: out = LN(A + B)*g + beta (bf16 out).
// ln_res3: out = LN(X + O0 + O1 + bias)*g + beta (f32 out), bf16 partials.
// ---------------------------------------------------------------------------
__device__ __forceinline__ float2 ld2(const float* p, long row, int tid) {
  return ((const float2*)(p + row * 512))[tid];
}
__device__ __forceinline__ float2 ld2(const bf16_t* p, long row, int tid) {
  bf16x2 v = *(const bf16x2*)(p + row * 512 + tid * 2);
  return make_float2((float)v[0], (float)v[1]);
}

__device__ __forceinline__ void ln_finish(
    float x0, float x1, const float* g, const float* be, int tid,
    int wave, int lane, float* of, bf16_t* ob, long row)
{
  float s = x0 + x1, ss = x0 * x0 + x1 * x1;
#pragma unroll
  for (int off = 1; off < 64; off <<= 1) {
    s  += __shfl_xor(s,  off, 64);
    ss += __shfl_xor(ss, off, 64);
  }
  __shared__ float sm[8];
  if (lane == 0) { sm[wave] = s; sm[4 + wave] = ss; }
  __syncthreads();
  s  = sm[0] + sm[1] + sm[2] + sm[3];
  ss = sm[4] + sm[5] + sm[6] + sm[7];
  const float mu = s * (1.f / 512.f);
  const float var = ss * (1.f / 512.f) - mu * mu;
  const float rs = rsqrtf(var + 1e-5f);
  const float2 gg = ((const float2*)g)[tid];
  const float2 bb = ((const float2*)be)[tid];
  const float o0 = (x0 - mu) * rs * gg.x + bb.x;
  const float o1 = (x1 - mu) * rs * gg.y + bb.y;
  if (of) ((float2*)(of + row * 512))[tid] = make_float2(o0, o1);
  if (ob) {
    bf16x2 t; t[0] = (bf16_t)o0; t[1] = (bf16_t)o1;
    *(bf16x2*)(ob + row * 512 + tid * 2) = t;
  }
}

__global__ __launch_bounds__(256) void ln_res(
    const bf16_t* __restrict__ A, const bf16_t* __restrict__ Bv,
    const float* __restrict__ g, const float* __restrict__ be,
    bf16_t* __restrict__ ob)
{
  const int row = blockIdx.x, tid = threadIdx.x;
  const float2 va = ld2(A,  (long)row, tid);
  const float2 vb = ld2(Bv, (long)row, tid);
  ln_finish(va.x + vb.x, va.y + vb.y, g, be, tid, tid >> 6, tid & 63,
            nullptr, ob, row);
}

__global__ __launch_bounds__(256) void ln_res3(
    const bf16_t* __restrict__ X, const bf16_t* __restrict__ O0,
    const bf16_t* __restrict__ O1, const float* __restrict__ bias,
    const float* __restrict__ g, const float* __restrict__ be,
    float* __restrict__ of)
{
  const int row = blockIdx.x, tid = threadIdx.x;
  const float2 vx = ld2(X,  (long)row, tid);
  const float2 v0 = ld2(O0, (long)row, tid);
  const float2 v1 = ld2(O1, (long)row, tid);
  const float2 vb = ((const float2*)bias)[tid];
  ln_finish(vx.x + v0.x + v1.x + vb.x, vx.y + v0.y + v1.y + vb.y,
            g, be, tid, tid >> 6, tid & 63, of, nullptr, row);
}

// ---------------------------------------------------------------------------
extern "C" void kernel_launch(void* const* d_in, const int* in_sizes, int n_in,
                              void* d_out, int out_size, void* d_ws, size_t ws_size,
                              hipStream_t stream)
{
  const float* Q   = (const float*)d_in[0];
  const float* K   = (const float*)d_in[1];
  const float* Wq  = (const float*)d_in[2];
  const float* bq  = (const float*)d_in[3];
  const float* Wk  = (const float*)d_in[4];
  const float* bk  = (const float*)d_in[5];
  const float* Wv  = (const float*)d_in[6];
  const float* bv  = (const float*)d_in[7];
  const float* W1  = (const float*)d_in[8];
  const float* b1  = (const float*)d_in[9];
  const float* W2  = (const float*)d_in[10];
  const float* b2  = (const float*)d_in[11];
  const float* W3  = (const float*)d_in[12];
  const float* b3  = (const float*)d_in[13];
  const float* g0  = (const float*)d_in[14];
  const float* be0 = (const float*)d_in[15];
  const float* g1  = (const float*)d_in[16];
  const float* be1 = (const float*)d_in[17];

  char* ws = (char*)d_ws;
  // weights (live whole run)
  bf16_t* Wqb = (bf16_t*)(ws + 0);
  bf16_t* Wkb = (bf16_t*)(ws + 524288);
  bf16_t* Wvb = (bf16_t*)(ws + 1048576);
  bf16_t* W1b = (bf16_t*)(ws + 1572864);
  bf16_t* W3b = (bf16_t*)(ws + 3670016);
  unsigned char* W2q = (unsigned char*)(ws + 5767168);   // 4 MiB fp8
  // activations, liveness-packed
  bf16_t* Qb  = (bf16_t*)(ws + 14155776);  // dead after proj3
  bf16_t* Kb  = (bf16_t*)(ws + 22544384);  // dead after proj3
  bf16_t* Qpb = (bf16_t*)(ws + 30932992);  // dead after LN0
  bf16_t* Kpb = (bf16_t*)(ws + 39321600);  // dead after attn
  bf16_t* VT  = (bf16_t*)(ws + 47710208);  // dead after attn
  bf16_t* Of  = (bf16_t*)(ws + 14155776);  // reuse Qb; dead after LN0
  bf16_t* Xb  = (bf16_t*)(ws + 22544384);  // reuse Kb; live till LN1
  bf16_t* H2  = (bf16_t*)(ws + 30932992);  // 32 MiB; reuse Qpb/Kpb/VT
  unsigned char* H1q = (unsigned char*)(ws + 64487424);  // 16 MiB fp8
  bf16_t* Off0 = (bf16_t*)(ws + 64487424); // 8 MiB; reuse H1q (dead)
  bf16_t* Off1 = (bf16_t*)(ws + 72876032); // 8 MiB
  float*  out = (float*)d_out;

  cast_all<<<15104, 256, 0, stream>>>(Q, K, Wq, Wk, Wv, W1, W2, W3,
                                      Qb, Kb, Wqb, Wkb, Wvb, W1b, W2q, W3b);
  proj3<<<dim3(64, 4, 3), 256, 0, stream>>>(Qb, Kb, Wqb, Wkb, Wvb, bq, bk, bv,
                                            Qpb, Kpb, VT);
  attn<<<1024, 256, 0, stream>>>(Qpb, Kpb, VT, Of);
  ln_res<<<8192, 256, 0, stream>>>(Of, Qpb, g0, be0, Xb);
  gemm_bt<128, true ><<<dim3(64, 16), 256, 0, stream>>>(Xb, W1b, b1, nullptr, nullptr, H1q, 1.0f, 2048, 512);
  ffn2_fp8<<<dim3(64, 16), 256, 0, stream>>>(H1q, W2q, b2, H2);
  ffn3_splitk<<<dim3(64, 4, 2), 256, 0, stream>>>(H2, W3b, Off0);
  ln_res3<<<8192, 256, 0, stream>>>(Xb, Off0, Off1, b3, g1, be1, out);
}